// Round 6
// baseline (94.479 us; speedup 1.0000x reference)
//
#include <hip/hip_runtime.h>
#include <math.h>

#define NQ 12
#define TPB 256

// R16 DIAGNOSTIC (resubmit; R5 attempt died to container infra): grid 256,
// each block runs 4 samples SEQUENTIALLY with the exact R2 per-sample
// structure (fastest verified: 33.9us kernel-side at grid 1024). Purpose:
// per-CU work is unchanged (4 samples/CU) but kernel wall time rises ~4x
// the solo-block time -> our kernel finally lands in the rocprof top-5
// WITH counters (VALUBusy / Occupancy / BANK_CONFLICT / FETCH), and the
// wall time itself separates hypotheses:
//   intra-block latency-bound  -> wall ~ 4 x 30 = 110-140us, VALUBusy low
//   inter-block contention     -> wall ~ 45-70us, VALUBusy higher
//   bank conflicts (model bug) -> SQ_LDS_BANK_CONFLICT large
// Next round reverts to grid 1024 + applies the counter-informed fix.
//
// Amp index j (12 bits), qubit q <-> j bit 11-q. Register layouts
// (t = thread 0..255 gives 8 bits, r = reg index 4 bits):
//   A: j = (r<<8)|t                  r = j[11:8] = qubits 0..3
//   B: j = (t[7:4]<<8)|(r<<4)|t[3:0] r = j[7:4]  = qubits 4..7
//   C: j = (t<<4)|r                  r = j[3:0]  = qubits 8..11
// B,C share wave bits j[11:10] -> B<->C roundtrips wave-local.
// Swizzle sg(j) = (j&~15)|((j^(j>>4)^(j>>8))&15); with kC=(t^(t>>4))&15:
//   sg(J_A(r)) = VA ^ 257r,  VA = (t&0xF0)|kC
//   sg(J_B(r)) = VB ^ 17r,   VB = ((t>>4)<<8)|kC
//   sg(J_C(r)) = VC ^ r,     VC = (t<<4)|kC
//   sg(P(j))   = Ft ^ G(r<<8), Ft per-thread, G const-folded
//
// Circuit (algebra verified R2-R10): init(C) = L0 RX product state with
// ring0 FOLDED via inverse perm; fused M_q = RX(L1)*RZ(L0)*RY(L0) as raw
// SU(2) [[a,-conj b],[b,conj a]] via VOP3P op_sel/neg (8 pk ops/pair);
// ring1 scatter; L1 RY (final RZ dropped); <Z_q> via partial reg-WHT +
// 6-stage lane-WHT butterfly.

__device__ __forceinline__ float2 pk_mul(float2 a, float2 b) {
    float2 d;
    asm("v_pk_mul_f32 %0, %1, %2" : "=v"(d) : "v"(a), "v"(b));
    return d;
}
__device__ __forceinline__ float2 pk_fma(float2 a, float2 b, float2 c) {
    float2 d;
    asm("v_pk_fma_f32 %0, %1, %2, %3" : "=v"(d) : "v"(a), "v"(b), "v"(c));
    return d;
}
// d.lo = a.hi*b.lo + c.lo ; d.hi = a.lo*b.hi + c.hi   (x<->y swap of a)
__device__ __forceinline__ float2 pk_fma_sw0(float2 a, float2 b, float2 c) {
    float2 d;
    asm("v_pk_fma_f32 %0, %1, %2, %3 op_sel:[1,0,0] op_sel_hi:[0,1,1]"
        : "=v"(d) : "v"(a), "v"(b), "v"(c));
    return d;
}
// d = a*(-b) + c
__device__ __forceinline__ float2 pk_fma_n1(float2 a, float2 b, float2 c) {
    float2 d;
    asm("v_pk_fma_f32 %0, %1, %2, %3 neg_lo:[0,1,0] neg_hi:[0,1,0]"
        : "=v"(d) : "v"(a), "v"(b), "v"(c));
    return d;
}
// d.lo = a.hi*(-b.lo) + c.lo ; d.hi = a.lo*(-b.hi) + c.hi
__device__ __forceinline__ float2 pk_fma_sw0n1(float2 a, float2 b, float2 c) {
    float2 d;
    asm("v_pk_fma_f32 %0, %1, %2, %3 op_sel:[1,0,0] op_sel_hi:[0,1,1] "
        "neg_lo:[0,1,0] neg_hi:[0,1,0]"
        : "=v"(d) : "v"(a), "v"(b), "v"(c));
    return d;
}

// variadic: commas inside the body are re-joined by __VA_ARGS__
#define FOR_PAIRS4(RB, ...) do {                                      \
    const int msk_ = 1 << (RB);                                       \
    _Pragma("unroll")                                                 \
    for (int h_ = 0; h_ < 8; ++h_) {                                  \
        const int i0 = ((h_ & ~(msk_ - 1)) << 1) | (h_ & (msk_ - 1)); \
        const int i1 = i0 | msk_;                                     \
        __VA_ARGS__;                                                  \
    } } while (0)

// strength-reduced swizzled addresses (VA/VB/VC in scope)
#define ADDR_A(r) (VA ^ (257 * (r)))
#define ADDR_B(r) (VB ^ (17 * (r)))
#define ADDR_C(r) (VC ^ (r))

// compiler-only fence for the barrier-less wave-local store->load aliasing
#define CFENCE asm volatile("" ::: "memory")

// wave-local roundtrip (same-wave LDS ordering, no barrier)
#define LOCAL_X(AS, AD) do {                                          \
    _Pragma("unroll")                                                 \
    for (int r_ = 0; r_ < 16; ++r_) S[AS(r_)] = v[r_];                \
    CFENCE;                                                           \
    _Pragma("unroll")                                                 \
    for (int r_ = 0; r_ < 16; ++r_) v[r_] = S[AD(r_)];                \
  } while (0)

// SU(2) gate [[a, -conj(b)], [b, conj(a)]], a=(ax,ay), b=(bx,by).
// gm[q] = { (ax,ax), (-ay,ay), (bx,bx), (-by,by) }  (broadcast LDS reads)
//   n0 = a*v0 - conj(b)*v1 ; n1 = b*v0 + conj(a)*v1   (8 pk ops / pair)
#define M_GATE(q, RB) do {                                                  \
        const float2 ar = gm[q][0];                                         \
        const float2 ai = gm[q][1];                                         \
        const float2 br = gm[q][2];                                         \
        const float2 bi = gm[q][3];                                         \
        FOR_PAIRS4(RB,                                                      \
            const float2 a0 = v[i0];                                        \
            const float2 a1 = v[i1];                                        \
            float2 n0 = pk_mul(a0, ar);                                     \
            n0 = pk_fma_sw0(a0, ai, n0);                                    \
            n0 = pk_fma_n1(a1, br, n0);                                     \
            n0 = pk_fma_sw0(a1, bi, n0);                                    \
            float2 n1 = pk_mul(a0, br);                                     \
            n1 = pk_fma_sw0(a0, bi, n1);                                    \
            n1 = pk_fma(a1, ar, n1);                                        \
            n1 = pk_fma_sw0n1(a1, ai, n1);                                  \
            v[i0] = n0; v[i1] = n1;                                         \
        );                                                                  \
    } while (0)

// gy[q] = { (c,c), (s,s) } ; n0 = c*v0 - s*v1, n1 = s*v0 + c*v1
#define RY_GATE(q, RB) do {                                                 \
        const float2 c2 = gy[q][0];                                         \
        const float2 s2 = gy[q][1];                                         \
        FOR_PAIRS4(RB,                                                      \
            float2 n0 = pk_fma_n1(v[i1], s2, pk_mul(v[i0], c2));            \
            float2 n1 = pk_fma(v[i0], s2, pk_mul(v[i1], c2));               \
            v[i0] = n0; v[i1] = n1;                                         \
        );                                                                  \
    } while (0)

// phase: gate qubit QB+d on r-bit 3-d (holds for A, B, C alike)
#define M_PHASE(QB)  do { _Pragma("unroll")                                 \
    for (int d_ = 0; d_ < 4; ++d_) M_GATE((QB) + d_, 3 - d_); } while (0)
#define RY_PHASE(QB) do { _Pragma("unroll")                                 \
    for (int d_ = 0; d_ < 4; ++d_) RY_GATE((QB) + d_, 3 - d_); } while (0)

__global__ __launch_bounds__(TPB, 4) void vqc_kernel(
    const float* __restrict__ x,    // [B, 12]
    const float* __restrict__ th,   // [2, 12, 2]
    const float* __restrict__ lm,   // [2, 12]
    float* __restrict__ out)        // [B, 12]
{
    __shared__ float2 S[4096];
    __shared__ float2 gm[12][4];    // fused M gate, duplicated entries
    __shared__ float2 gy[12][2];    // L1 RY, duplicated (c,c),(s,s)
    __shared__ float2 coI[12];      // L0 RX half-angle (c,s)
    __shared__ float red[4 * 12];

    const int t = threadIdx.x;
    const int l = t & 63;
    const int w = t >> 6;

    // strength-reduced address bases
    const int kC = (t ^ (t >> 4)) & 15;
    const int VA = (t & 0xF0) | kC;
    const int VB = ((t >> 4) << 8) | kC;
    const int VC = (t << 4) | kC;
    // ring per-thread part: Ft = sg(P-image of t) (GF(2)-linear split)
    int Ft;
    {
        int yt = t ^ (t >> 1); yt ^= yt >> 2; yt ^= yt >> 4; yt ^= yt >> 8;
        int pt = (yt & 0x7FF) | ((__popc(t) & 1) << 11);
        Ft = (pt & ~15) | ((pt ^ (pt >> 4) ^ (pt >> 8)) & 15);
    }

    // ---- 4 samples, sequential, identical R2 structure each ----
    for (int s = 0; s < 4; ++s) {
        const int b = blockIdx.x * 4 + s;

        // ---- cooperative coefficient precompute ----
        if (t < 12) {
            float h = 0.5f * lm[t] * x[b * NQ + t];
            float c, sn; __sincosf(h, &sn, &c);
            coI[t] = make_float2(c, sn);
        } else if (t < 24) {
            int q = t - 12;
            float h = 0.5f * th[24 + 2 * q];
            float c, sn; __sincosf(h, &sn, &c);
            gy[q][0] = make_float2(c, c);
            gy[q][1] = make_float2(sn, sn);
        } else if (t < 36) {
            int q = t - 24;
            float ha = 0.5f * lm[12 + q] * x[b * NQ + q];  // L1 RX half
            float hy = 0.5f * th[2 * q];                   // L0 RY half
            float hz = 0.5f * th[2 * q + 1];               // L0 RZ half
            float ca, sa, cy, sy, cz, sz;
            __sincosf(ha, &sa, &ca);
            __sincosf(hy, &sy, &cy);
            __sincosf(hz, &sz, &cz);
            // M = RX(a) RZ(z) RY(y): alpha = M00, beta = M10 (R9-verified)
            float ax = ca*cy*cz + sa*sy*sz;
            float ay = -(ca*cy*sz + sa*sy*cz);
            float bx = ca*sy*cz - sa*cy*sz;
            float by = ca*sy*sz - sa*cy*cz;
            gm[q][0] = make_float2(ax, ax);
            gm[q][1] = make_float2(-ay, ay);
            gm[q][2] = make_float2(bx, bx);
            gm[q][3] = make_float2(-by, by);
        }
        __syncthreads();                                   // B1

        float2 v[16];

        // ---- init in layout C: L0 RX product state, ring0 folded ----
        // (R10-verified) i = P^{-1}(j), j = (t<<4)|r:
        //  i0=r0^r1 (q11), i1=r1^r2 (q10), i2=r2^r3 (q9), i3=r3^t0 (q8),
        //  i4..i9 = gray(t) bits 0..5 (qubits 7..2),
        //  i10 = t6^r0^t7 (q1), i11 = r0^t7 (q0)
        {
            const int g = (t ^ (t >> 1)) & 0x3F;
            float Pt = 1.0f;
#pragma unroll
            for (int m = 0; m < 6; ++m) {
                float2 cs = coI[7 - m];
                Pt *= ((g >> m) & 1) ? cs.y : cs.x;
            }
            const int ct = __popc(g);
            const int t0 = t & 1, t7 = (t >> 7) & 1;
            const int e1 = ((t >> 6) ^ (t >> 7)) & 1;
            float2 q11 = coI[11], q10 = coI[10], q9 = coI[9],
                   q8 = coI[8], q1 = coI[1], q0 = coI[0];
            const float u8  = t0 ? q8.y : q8.x;     // qubit 8, key t0^r3
            const float u8n = t0 ? q8.x : q8.y;
            const float u1  = e1 ? q1.y : q1.x;     // qubit 1, key e1^r0
            const float u1n = e1 ? q1.x : q1.y;
            const float u0  = t7 ? q0.y : q0.x;     // qubit 0, key t7^r0
            const float u0n = t7 ? q0.x : q0.y;
#pragma unroll
            for (int r = 0; r < 16; ++r) {
                const int r0 = r & 1, r1 = (r >> 1) & 1, r2 = (r >> 2) & 1,
                          r3 = (r >> 3) & 1;
                const int b11 = r0 ^ r1, b10 = r1 ^ r2, b9 = r2 ^ r3;
                float m = Pt * (b11 ? q11.y : q11.x) * (b10 ? q10.y : q10.x)
                             * (b9 ? q9.y : q9.x) * (r3 ? u8n : u8)
                             * (r0 ? u1n : u1) * (r0 ? u0n : u0);
                int k = (ct + b11 + b10 + b9 + (r3 ^ t0) + (r0 ^ e1) + (r0 ^ t7)) & 3;
                v[r].x = (k == 0) ? m : ((k == 2) ? -m : 0.0f);
                v[r].y = (k == 3) ? m : ((k == 1) ? -m : 0.0f);
            }
        }

        // ---- fused M-pass (L0 RY,RZ + L1 RX), C -> B -> A ----
        M_PHASE(8);                       // qubits 8..11 in C
        LOCAL_X(ADDR_C, ADDR_B);          // X1: wave-local
        M_PHASE(4);                       // qubits 4..7  in B
#pragma unroll
        for (int r = 0; r < 16; ++r) S[ADDR_B(r)] = v[r];
        __syncthreads();                  // B2 (cross B -> A)
#pragma unroll
        for (int r = 0; r < 16; ++r) v[r] = S[ADDR_A(r)];
        M_PHASE(0);                       // qubits 0..3  in A

        // ---- layer-1 CNOT ring: A -> A (addr = Ft ^ const G(r<<8)) ----
        __syncthreads();                  // B3 (all A-reads done)
#pragma unroll
        for (int r = 0; r < 16; ++r) {
            const int jr = r << 8;
            int yr = jr ^ (jr >> 1); yr ^= yr >> 2; yr ^= yr >> 4; yr ^= yr >> 8;
            const int pr = (yr & 0x7FF) | (((__popc(jr) ^ (jr >> 11)) & 1) << 11);
            const int Gr = (pr & ~15) | ((pr ^ (pr >> 4) ^ (pr >> 8)) & 15);
            S[Ft ^ Gr] = v[r];
        }
        __syncthreads();                  // B4
#pragma unroll
        for (int r = 0; r < 16; ++r) v[r] = S[ADDR_A(r)];

        // ---- layer-1 RY (final RZ dropped), A -> B -> C ----
        RY_PHASE(0);                      // in A
        // no barrier: store hits exactly the addresses THIS thread read at
        // the B4 gather; no other thread touches these slots (R2-verified).
#pragma unroll
        for (int r = 0; r < 16; ++r) S[ADDR_A(r)] = v[r];
        __syncthreads();                  // B5 (cross A -> B)
#pragma unroll
        for (int r = 0; r < 16; ++r) v[r] = S[ADDR_B(r)];
        RY_PHASE(4);                      // in B
        LOCAL_X(ADDR_B, ADDR_C);          // X5: wave-local
        RY_PHASE(8);                      // in C

        // ---- measurement in C ----
        // qubits 8..11 <-> r bits 3..0 ; qubits 2..7 <-> lane bits 5..0
        // (lane bit k = j[4+k] = qubit 7-k) ; qubits 0,1 <-> wave bits 1,0
        float p[16];
#pragma unroll
        for (int r = 0; r < 16; ++r)
            p[r] = fmaf(v[r].x, v[r].x, v[r].y * v[r].y);
        float sA[8], dA[8];
#pragma unroll
        for (int k = 0; k < 8; ++k) {
            sA[k] = p[2 * k] + p[2 * k + 1];
            dA[k] = p[2 * k] - p[2 * k + 1];
        }
        float z11 = ((dA[0] + dA[1]) + (dA[2] + dA[3]))
                  + ((dA[4] + dA[5]) + (dA[6] + dA[7]));
        float sC[4], dC[4];
#pragma unroll
        for (int k = 0; k < 4; ++k) {
            sC[k] = sA[2 * k] + sA[2 * k + 1];
            dC[k] = sA[2 * k] - sA[2 * k + 1];
        }
        float z10 = (dC[0] + dC[1]) + (dC[2] + dC[3]);
        float e0 = sC[0] + sC[1], f0 = sC[0] - sC[1];
        float e1s = sC[2] + sC[3], f1 = sC[2] - sC[3];
        float vals[5];
        vals[0] = e0 + e1s;               // ptot
        vals[1] = e0 - e1s;               // z8  (r bit3)
        vals[2] = f0 + f1;                // z9  (r bit2)
        vals[3] = z10;                    // z10 (r bit1)
        vals[4] = z11;                    // z11 (r bit0)

        // 6-stage WHT butterfly: lane L ends with sum_l (-1)^{popc(L&l)} x_l
#pragma unroll
        for (int k = 0; k < 6; ++k) {
            const float sgn = ((l >> k) & 1) ? -1.f : 1.f;
#pragma unroll
            for (int m = 0; m < 5; ++m) {
                float tmp = __shfl_xor(vals[m], 1 << k, 64);
                vals[m] = fmaf(sgn, vals[m], tmp);
            }
        }
        if (l == 0) {                     // wave totals
            red[w * 12 + 0]  = vals[0];   // ptot (for qubits 0,1)
            red[w * 12 + 8]  = vals[1];
            red[w * 12 + 9]  = vals[2];
            red[w * 12 + 10] = vals[3];
            red[w * 12 + 11] = vals[4];
        } else if (__popc(l) == 1) {      // lane-bit sums: qubits 2..7
            int q = 8 - __ffs(l);         // l=1<<k -> q = 7-k
            red[w * 12 + q] = vals[0];
        }
        __syncthreads();                  // B6
        if (t < NQ) {
            float acc = 0.f;
#pragma unroll
            for (int ww = 0; ww < 4; ++ww) {
                if (t < 2) {
                    float pv = red[ww * 12 + 0];
                    acc += ((ww >> (1 - t)) & 1) ? -pv : pv;
                } else {
                    acc += red[ww * 12 + t];
                }
            }
            out[b * NQ + t] = acc;
        }
        __syncthreads();                  // Bloop (red/coI/gm reuse)
    }
}

extern "C" void kernel_launch(void* const* d_in, const int* in_sizes, int n_in,
                              void* d_out, int out_size, void* d_ws, size_t ws_size,
                              hipStream_t stream) {
    const int B = in_sizes[0] / NQ;  // 1024
    vqc_kernel<<<B / 4, TPB, 0, stream>>>((const float*)d_in[0],
                                          (const float*)d_in[1],
                                          (const float*)d_in[2],
                                          (float*)d_out);
}

// Round 7
// 77.710 us; speedup vs baseline: 1.2158x; 1.2158x over previous
//
#include <hip/hip_runtime.h>
#include <math.h>

#define NQ 12
#define TPB 64

// R17: ONE WAVE = ONE SAMPLE. TPB 64, grid 1024, v[64] float2/lane = the
// whole 4096-amp state in one wave (128 VGPR state).
// R16 diagnostic: solo sample = 10.8us, VALUBusy 20%, bank conflicts ~0,
// 4-way block concurrency gives only 1.26x -> stall-bound on cross-wave
// structure (barriers, 5 LDS roundtrips, lockstep phases), not on any pipe.
// This design deletes the whole class: ZERO barriers (all LDS wave-local,
// DS is in-order per wave; CFENCE stops compiler reordering), 3 LDS
// roundtrips instead of 5, in-wave measurement with direct global stores.
// Occupancy: LDS 33.4KB -> 4 blocks/CU, 1 wave/SIMD, 1 sample per SIMD.
//
// Layouts (lane l 6 bits, reg r 6 bits, amp index j, qubit q <-> bit 11-q):
//   C6: j = (l<<6)|r   reg bits j[5:0]  = qubits 6..11 (rb <-> q 11-rb)
//   A6: j = (r<<6)|l   reg bits j[11:6] = qubits 0..5  (rb <-> q 5-rb)
// Swizzle (bank-conflict-free both ways, GF(2)-linear, bijective):
//   E(j) = (j & ~15) | ((j ^ (j>>6)) & 15)
//   C6 access: elem = VC ^ r,                VC = (l<<6)|(l&15)
//   A6 access: elem = l ^ ((r<<6)|(r&15))
// Ring map (verified R2): p_k = XOR_{m>=k} j_m (k<=10), p11 = XOR_{m<=10} j_m
//   P and E linear + (r<<6, l) disjoint -> ring store addr splits into
//   per-lane FlP = E(P(l)) ^ compile-time E(P(r<<6)).
// Init (L0 RX product state with ring0 folded, verified R2 bit relations,
// re-expressed in j bits): key b_k = j_k ^ j_{k+1} (k=0..9),
//   b10 = j10^j11^j0, b11 = j11^j0; factor for key k is qubit 11-k
//   (k=0..9 -> q11..q2), b10 -> q1, b11 -> q0; phase = (-i)^(sum of keys).
//
// Circuit (algebra verified R2-R10): init(C6) -> M q6..11 -> T1 -> M q0..5
// -> ring1 scatter (A6->A6) -> RY q0..5 -> T2 -> RY q6..11 -> measure(C6).
// M_q = RX(L1)*RZ(L0)*RY(L0) as raw SU(2) [[a,-conj b],[b,conj a]] via
// VOP3P op_sel/neg (8 pk ops/pair); final RZ dropped (phase-only).

__device__ __forceinline__ float2 pk_mul(float2 a, float2 b) {
    float2 d;
    asm("v_pk_mul_f32 %0, %1, %2" : "=v"(d) : "v"(a), "v"(b));
    return d;
}
__device__ __forceinline__ float2 pk_fma(float2 a, float2 b, float2 c) {
    float2 d;
    asm("v_pk_fma_f32 %0, %1, %2, %3" : "=v"(d) : "v"(a), "v"(b), "v"(c));
    return d;
}
// d.lo = a.hi*b.lo + c.lo ; d.hi = a.lo*b.hi + c.hi   (x<->y swap of a)
__device__ __forceinline__ float2 pk_fma_sw0(float2 a, float2 b, float2 c) {
    float2 d;
    asm("v_pk_fma_f32 %0, %1, %2, %3 op_sel:[1,0,0] op_sel_hi:[0,1,1]"
        : "=v"(d) : "v"(a), "v"(b), "v"(c));
    return d;
}
// d = a*(-b) + c
__device__ __forceinline__ float2 pk_fma_n1(float2 a, float2 b, float2 c) {
    float2 d;
    asm("v_pk_fma_f32 %0, %1, %2, %3 neg_lo:[0,1,0] neg_hi:[0,1,0]"
        : "=v"(d) : "v"(a), "v"(b), "v"(c));
    return d;
}
// d.lo = a.hi*(-b.lo) + c.lo ; d.hi = a.lo*(-b.hi) + c.hi
__device__ __forceinline__ float2 pk_fma_sw0n1(float2 a, float2 b, float2 c) {
    float2 d;
    asm("v_pk_fma_f32 %0, %1, %2, %3 op_sel:[1,0,0] op_sel_hi:[0,1,1] "
        "neg_lo:[0,1,0] neg_hi:[0,1,0]"
        : "=v"(d) : "v"(a), "v"(b), "v"(c));
    return d;
}

// ring map (verified R2) and swizzle -- GF(2)-linear; constant-fold for
// literal args inside unrolled loops.
__device__ __forceinline__ int Pmap(int j) {
    int y = j ^ (j >> 1); y ^= y >> 2; y ^= y >> 4; y ^= y >> 8;
    return (y & 0x7FF) | (((__popc(j) ^ (j >> 11)) & 1) << 11);
}
__device__ __forceinline__ int Esw(int j) {
    return (j & ~15) | ((j ^ (j >> 6)) & 15);
}

// variadic: commas inside the body are re-joined by __VA_ARGS__
#define FOR_PAIRS6(RB, ...) do {                                      \
    const int msk_ = 1 << (RB);                                       \
    _Pragma("unroll")                                                 \
    for (int h_ = 0; h_ < 32; ++h_) {                                 \
        const int i0 = ((h_ & ~(msk_ - 1)) << 1) | (h_ & (msk_ - 1)); \
        const int i1 = i0 | msk_;                                     \
        __VA_ARGS__;                                                  \
    } } while (0)

// compiler-only fence: stops reordering of this lane's LDS ops; wave-level
// in-order DS execution provides the cross-lane visibility (R2-verified).
#define CFENCE asm volatile("" ::: "memory")

// SU(2) gate [[a, -conj(b)], [b, conj(a)]], a=(ax,ay), b=(bx,by).
// gm[q] = { (ax,ax), (-ay,ay), (bx,bx), (-by,by) }  (broadcast LDS reads)
//   n0 = a*v0 - conj(b)*v1 ; n1 = b*v0 + conj(a)*v1   (8 pk ops / pair)
#define M_GATE(q, RB) do {                                                  \
        const float2 ar = gm[q][0];                                         \
        const float2 ai = gm[q][1];                                         \
        const float2 br = gm[q][2];                                         \
        const float2 bi = gm[q][3];                                         \
        FOR_PAIRS6(RB,                                                      \
            const float2 a0 = v[i0];                                        \
            const float2 a1 = v[i1];                                        \
            float2 n0 = pk_mul(a0, ar);                                     \
            n0 = pk_fma_sw0(a0, ai, n0);                                    \
            n0 = pk_fma_n1(a1, br, n0);                                     \
            n0 = pk_fma_sw0(a1, bi, n0);                                    \
            float2 n1 = pk_mul(a0, br);                                     \
            n1 = pk_fma_sw0(a0, bi, n1);                                    \
            n1 = pk_fma(a1, ar, n1);                                        \
            n1 = pk_fma_sw0n1(a1, ai, n1);                                  \
            v[i0] = n0; v[i1] = n1;                                         \
        );                                                                  \
    } while (0)

// gy[q] = { (c,c), (s,s) } ; n0 = c*v0 - s*v1, n1 = s*v0 + c*v1
#define RY_GATE(q, RB) do {                                                 \
        const float2 c2 = gy[q][0];                                         \
        const float2 s2 = gy[q][1];                                         \
        FOR_PAIRS6(RB,                                                      \
            float2 n0 = pk_fma_n1(v[i1], s2, pk_mul(v[i0], c2));            \
            float2 n1 = pk_fma(v[i0], s2, pk_mul(v[i1], c2));               \
            v[i0] = n0; v[i1] = n1;                                         \
        );                                                                  \
    } while (0)

__global__ __launch_bounds__(TPB, 1) void vqc_kernel(
    const float* __restrict__ x,    // [B, 12]
    const float* __restrict__ th,   // [2, 12, 2]
    const float* __restrict__ lm,   // [2, 12]
    float* __restrict__ out)        // [B, 12]
{
    __shared__ float2 S[4096];
    __shared__ float2 gm[12][4];    // fused M gate, duplicated entries
    __shared__ float2 gy[12][2];    // L1 RY, duplicated (c,c),(s,s)
    __shared__ float2 coI[12];      // L0 RX half-angle (c,s)

    const int b = blockIdx.x;
    const int l = threadIdx.x;      // 0..63: the single wave's lane

    // ---- coefficient precompute (lanes 0..35, same wave -> no barrier) ----
    if (l < 12) {
        float h = 0.5f * lm[l] * x[b * NQ + l];
        float c, sn; __sincosf(h, &sn, &c);
        coI[l] = make_float2(c, sn);
    } else if (l < 24) {
        int q = l - 12;
        float h = 0.5f * th[24 + 2 * q];
        float c, sn; __sincosf(h, &sn, &c);
        gy[q][0] = make_float2(c, c);
        gy[q][1] = make_float2(sn, sn);
    } else if (l < 36) {
        int q = l - 24;
        float ha = 0.5f * lm[12 + q] * x[b * NQ + q];  // L1 RX half
        float hy = 0.5f * th[2 * q];                   // L0 RY half
        float hz = 0.5f * th[2 * q + 1];               // L0 RZ half
        float ca, sa, cy, sy, cz, sz;
        __sincosf(ha, &sa, &ca);
        __sincosf(hy, &sy, &cy);
        __sincosf(hz, &sz, &cz);
        // M = RX(a) RZ(z) RY(y): alpha = M00, beta = M10 (R9-verified)
        float ax = ca*cy*cz + sa*sy*sz;
        float ay = -(ca*cy*sz + sa*sy*cz);
        float bx = ca*sy*cz - sa*cy*sz;
        float by = ca*sy*sz - sa*cy*cz;
        gm[q][0] = make_float2(ax, ax);
        gm[q][1] = make_float2(-ay, ay);
        gm[q][2] = make_float2(bx, bx);
        gm[q][3] = make_float2(-by, by);
    }
    CFENCE;                          // same-wave LDS ordering is in-order

    float2 v[64];

    // ---- init in C6: L0 RX product state, ring0 folded ----
    {
        float2 cI[12];
#pragma unroll
        for (int q = 0; q < 12; ++q) cI[q] = coI[q];   // broadcast reads

        const int l0 = l & 1, l1 = (l >> 1) & 1, l2 = (l >> 2) & 1,
                  l3 = (l >> 3) & 1, l4 = (l >> 4) & 1, l5 = (l >> 5) & 1;
        // lane-only keys b6..b9 -> qubits 5..2
        const float Pl = ((l0 ^ l1) ? cI[5].y : cI[5].x)
                       * ((l1 ^ l2) ? cI[4].y : cI[4].x)
                       * ((l2 ^ l3) ? cI[3].y : cI[3].x)
                       * ((l3 ^ l4) ? cI[2].y : cI[2].x);
        const int Sl = (l0 ^ l1) + (l1 ^ l2) + (l2 ^ l3) + (l3 ^ l4);
        // mixed keys: b5 = r5^l0 (q6), b10 = r0^(l4^l5) (q1), b11 = r0^l5 (q0)
        const int e10 = l4 ^ l5;
        float u6[2], u1t[2], u0t[2];
        u6[0]  = l0  ? cI[6].y : cI[6].x;  u6[1]  = l0  ? cI[6].x : cI[6].y;
        u1t[0] = e10 ? cI[1].y : cI[1].x;  u1t[1] = e10 ? cI[1].x : cI[1].y;
        u0t[0] = l5  ? cI[0].y : cI[0].x;  u0t[1] = l5  ? cI[0].x : cI[0].y;
        int c6a[2], c1a[2], c0a[2];
        c6a[0] = l0;  c6a[1] = 1 - l0;
        c1a[0] = e10; c1a[1] = 1 - e10;
        c0a[0] = l5;  c0a[1] = 1 - l5;
#pragma unroll
        for (int r = 0; r < 64; ++r) {
            const int r0 = r & 1, r1 = (r >> 1) & 1, r2 = (r >> 2) & 1,
                      r3 = (r >> 3) & 1, r4 = (r >> 4) & 1, r5 = (r >> 5) & 1;
            const int b0 = r0 ^ r1, b1 = r1 ^ r2, b2 = r2 ^ r3,
                      b3 = r3 ^ r4, b4 = r4 ^ r5;
            float m = Pl * (b0 ? cI[11].y : cI[11].x)
                         * (b1 ? cI[10].y : cI[10].x)
                         * (b2 ? cI[9].y  : cI[9].x)
                         * (b3 ? cI[8].y  : cI[8].x)
                         * (b4 ? cI[7].y  : cI[7].x)
                         * u6[r5] * u1t[r0] * u0t[r0];
            const int k = (b0 + b1 + b2 + b3 + b4 + Sl
                           + c6a[r5] + c1a[r0] + c0a[r0]) & 3;
            v[r].x = (k == 0) ? m : ((k == 2) ? -m : 0.0f);
            v[r].y = (k == 3) ? m : ((k == 1) ? -m : 0.0f);
        }
    }

    const int VC = (l << 6) | (l & 15);   // C6 elem base

    // ---- M gates on qubits 6..11 (C6, reg-local: q <-> rb 11-q) ----
    M_GATE(6, 5); M_GATE(7, 4); M_GATE(8, 3);
    M_GATE(9, 2); M_GATE(10, 1); M_GATE(11, 0);

    // ---- T1: C6 -> A6 (wave-local, no barrier) ----
#pragma unroll
    for (int r = 0; r < 64; ++r) S[VC ^ r] = v[r];
    CFENCE;
#pragma unroll
    for (int r = 0; r < 64; ++r) v[r] = S[l ^ ((r << 6) | (r & 15))];

    // ---- M gates on qubits 0..5 (A6, reg-local: q <-> rb 5-q) ----
    M_GATE(0, 5); M_GATE(1, 4); M_GATE(2, 3);
    M_GATE(3, 2); M_GATE(4, 1); M_GATE(5, 0);

    // ---- ring1 scatter A6 -> A6: addr = E(P(l)) ^ E(P(r<<6)) ----
    {
        const int FlP = Esw(Pmap(l));
#pragma unroll
        for (int r = 0; r < 64; ++r) S[FlP ^ Esw(Pmap(r << 6))] = v[r];
        CFENCE;
#pragma unroll
        for (int r = 0; r < 64; ++r) v[r] = S[l ^ ((r << 6) | (r & 15))];
    }

    // ---- L1 RY on qubits 0..5 (A6) ----
    RY_GATE(0, 5); RY_GATE(1, 4); RY_GATE(2, 3);
    RY_GATE(3, 2); RY_GATE(4, 1); RY_GATE(5, 0);

    // ---- T2: A6 -> C6 ----
#pragma unroll
    for (int r = 0; r < 64; ++r) S[l ^ ((r << 6) | (r & 15))] = v[r];
    CFENCE;
#pragma unroll
    for (int r = 0; r < 64; ++r) v[r] = S[VC ^ r];

    // ---- L1 RY on qubits 6..11 (C6) ----
    RY_GATE(6, 5); RY_GATE(7, 4); RY_GATE(8, 3);
    RY_GATE(9, 2); RY_GATE(10, 1); RY_GATE(11, 0);

    // ---- measurement (C6, fully in-wave) ----
    // reg bit rb <-> qubit 11-rb ; lane bit k <-> qubit 5-k
    float vals[7];                   // {ptot, z_rb0(q11), ..., z_rb5(q6)}
#pragma unroll
    for (int m = 0; m < 7; ++m) vals[m] = 0.0f;
#pragma unroll
    for (int r = 0; r < 64; ++r) {
        const float pr = fmaf(v[r].x, v[r].x, v[r].y * v[r].y);
        vals[0] += pr;
        vals[1] += (r & 1)  ? -pr : pr;
        vals[2] += (r & 2)  ? -pr : pr;
        vals[3] += (r & 4)  ? -pr : pr;
        vals[4] += (r & 8)  ? -pr : pr;
        vals[5] += (r & 16) ? -pr : pr;
        vals[6] += (r & 32) ? -pr : pr;
    }
    // 6-stage WHT butterfly: lane L ends with sum_l (-1)^{popc(L&l)} x_l
#pragma unroll
    for (int k = 0; k < 6; ++k) {
        const float sgn = ((l >> k) & 1) ? -1.f : 1.f;
#pragma unroll
        for (int m = 0; m < 7; ++m) {
            float tmp = __shfl_xor(vals[m], 1 << k, 64);
            vals[m] = fmaf(sgn, vals[m], tmp);
        }
    }
    if (l == 0) {                    // full sums: reg qubits 6..11
        out[b * NQ + 11] = vals[1];
        out[b * NQ + 10] = vals[2];
        out[b * NQ + 9]  = vals[3];
        out[b * NQ + 8]  = vals[4];
        out[b * NQ + 7]  = vals[5];
        out[b * NQ + 6]  = vals[6];
    } else if (__popc(l) == 1) {     // signed ptot sums: lane qubits
        out[b * NQ + (6 - __ffs(l))] = vals[0];   // l=1<<k -> q = 5-k
    }
}

extern "C" void kernel_launch(void* const* d_in, const int* in_sizes, int n_in,
                              void* d_out, int out_size, void* d_ws, size_t ws_size,
                              hipStream_t stream) {
    const int B = in_sizes[0] / NQ;  // 1024
    vqc_kernel<<<B, TPB, 0, stream>>>((const float*)d_in[0],
                                      (const float*)d_in[1],
                                      (const float*)d_in[2],
                                      (float*)d_out);
}

// Round 8
// 74.625 us; speedup vs baseline: 1.2660x; 1.0413x over previous
//
#include <hip/hip_runtime.h>
#include <math.h>

#define NQ 12
#define TPB 256

// R18: CODE-SIZE ATTACK. Evidence (R2/R16/R17): per-CU throughput is
// ~9-11us/sample across 3 radically different sync structures; VALU ~20%,
// DS ~10-25%, conflicts 0, HBM 0; TLP x4 -> only 1.26x. Everything points
// at INSTRUCTION DELIVERY: ~24KB straight-line body, zero I$ reuse within
// a wave, shared L1I thrashed by staggered waves. Fix: loop the 24 gate
// applications instead of unrolling them. Each phase = `#pragma unroll 1`
// 4-iteration loop over ONE gate body that always targets reg-bit 3, then
// a static register ROTATION (bit k -> k+1; rho^4 = identity restores the
// layout at phase end). Gate d then acts on original reg-bit 3-d, exactly
// R2's sequencing. All v[] indices remain compile-time constants (no
// scratch). Code ~24KB -> ~10KB; +32 v_movs per gate (~6% issue).
// Everything else is byte-for-byte the R2 kernel (fastest verified:
// 33.9us kernel-side).
//
// Amp index j (12 bits), qubit q <-> j bit 11-q. Register layouts
// (t = thread 0..255 gives 8 bits, r = reg index 4 bits):
//   A: j = (r<<8)|t                  r = j[11:8] = qubits 0..3
//   B: j = (t[7:4]<<8)|(r<<4)|t[3:0] r = j[7:4]  = qubits 4..7
//   C: j = (t<<4)|r                  r = j[3:0]  = qubits 8..11
// B,C share wave bits j[11:10] -> B<->C roundtrips wave-local.
// Swizzle sg(j) = (j&~15)|((j^(j>>4)^(j>>8))&15); with kC=(t^(t>>4))&15:
//   sg(J_A(r)) = VA ^ 257r,  VA = (t&0xF0)|kC
//   sg(J_B(r)) = VB ^ 17r,   VB = ((t>>4)<<8)|kC
//   sg(J_C(r)) = VC ^ r,     VC = (t<<4)|kC
//   sg(P(j))   = Ft ^ G(r<<8), Ft per-thread, G const-folded
//
// Circuit (algebra verified R2-R10): init(C) = L0 RX product state with
// ring0 FOLDED via inverse perm; fused M_q = RX(L1)*RZ(L0)*RY(L0) as raw
// SU(2) [[a,-conj b],[b,conj a]] via VOP3P op_sel/neg (8 pk ops/pair);
// ring1 scatter; L1 RY (final RZ dropped); <Z_q> via partial reg-WHT +
// 6-stage lane-WHT butterfly.

__device__ __forceinline__ float2 pk_mul(float2 a, float2 b) {
    float2 d;
    asm("v_pk_mul_f32 %0, %1, %2" : "=v"(d) : "v"(a), "v"(b));
    return d;
}
__device__ __forceinline__ float2 pk_fma(float2 a, float2 b, float2 c) {
    float2 d;
    asm("v_pk_fma_f32 %0, %1, %2, %3" : "=v"(d) : "v"(a), "v"(b), "v"(c));
    return d;
}
// d.lo = a.hi*b.lo + c.lo ; d.hi = a.lo*b.hi + c.hi   (x<->y swap of a)
__device__ __forceinline__ float2 pk_fma_sw0(float2 a, float2 b, float2 c) {
    float2 d;
    asm("v_pk_fma_f32 %0, %1, %2, %3 op_sel:[1,0,0] op_sel_hi:[0,1,1]"
        : "=v"(d) : "v"(a), "v"(b), "v"(c));
    return d;
}
// d = a*(-b) + c
__device__ __forceinline__ float2 pk_fma_n1(float2 a, float2 b, float2 c) {
    float2 d;
    asm("v_pk_fma_f32 %0, %1, %2, %3 neg_lo:[0,1,0] neg_hi:[0,1,0]"
        : "=v"(d) : "v"(a), "v"(b), "v"(c));
    return d;
}
// d.lo = a.hi*(-b.lo) + c.lo ; d.hi = a.lo*(-b.hi) + c.hi
__device__ __forceinline__ float2 pk_fma_sw0n1(float2 a, float2 b, float2 c) {
    float2 d;
    asm("v_pk_fma_f32 %0, %1, %2, %3 op_sel:[1,0,0] op_sel_hi:[0,1,1] "
        "neg_lo:[0,1,0] neg_hi:[0,1,0]"
        : "=v"(d) : "v"(a), "v"(b), "v"(c));
    return d;
}

// pairs for reg-bit 3: (h, h+8), h = 0..7
#define FOR_PAIRS_RB3(...) do {                                       \
    _Pragma("unroll")                                                 \
    for (int h_ = 0; h_ < 8; ++h_) {                                  \
        const int i0 = h_;                                            \
        const int i1 = h_ | 8;                                        \
        __VA_ARGS__;                                                  \
    } } while (0)

// register rotation rho: element at index o moves to ((o<<1)&15)|(o>>3)
// (bit k -> bit k+1 mod 4). rho^4 = identity. Static indices only.
#define ROT4 do {                                                     \
    float2 t_[16];                                                    \
    _Pragma("unroll")                                                 \
    for (int o_ = 0; o_ < 16; ++o_)                                   \
        t_[((o_ << 1) & 15) | (o_ >> 3)] = v[o_];                     \
    _Pragma("unroll")                                                 \
    for (int i_ = 0; i_ < 16; ++i_) v[i_] = t_[i_];                   \
  } while (0)

// strength-reduced swizzled addresses (VA/VB/VC in scope)
#define ADDR_A(r) (VA ^ (257 * (r)))
#define ADDR_B(r) (VB ^ (17 * (r)))
#define ADDR_C(r) (VC ^ (r))

// compiler-only fence for the barrier-less wave-local store->load aliasing
#define CFENCE asm volatile("" ::: "memory")

// wave-local roundtrip (same-wave LDS ordering, no barrier)
#define LOCAL_X(AS, AD) do {                                          \
    _Pragma("unroll")                                                 \
    for (int r_ = 0; r_ < 16; ++r_) S[AS(r_)] = v[r_];                \
    CFENCE;                                                           \
    _Pragma("unroll")                                                 \
    for (int r_ = 0; r_ < 16; ++r_) v[r_] = S[AD(r_)];                \
  } while (0)

// SU(2) gate [[a, -conj(b)], [b, conj(a)]], a=(ax,ay), b=(bx,by).
// gm[q] = { (ax,ax), (-ay,ay), (bx,bx), (-by,by) }  (broadcast LDS reads)
//   n0 = a*v0 - conj(b)*v1 ; n1 = b*v0 + conj(a)*v1   (8 pk ops / pair)
// Acts on reg-bit 3; q may be a runtime value (looped phases).
#define M_GATE_RB3(q) do {                                                  \
        const float2 ar = gm[q][0];                                         \
        const float2 ai = gm[q][1];                                         \
        const float2 br = gm[q][2];                                         \
        const float2 bi = gm[q][3];                                         \
        FOR_PAIRS_RB3(                                                      \
            const float2 a0 = v[i0];                                        \
            const float2 a1 = v[i1];                                        \
            float2 n0 = pk_mul(a0, ar);                                     \
            n0 = pk_fma_sw0(a0, ai, n0);                                    \
            n0 = pk_fma_n1(a1, br, n0);                                     \
            n0 = pk_fma_sw0(a1, bi, n0);                                    \
            float2 n1 = pk_mul(a0, br);                                     \
            n1 = pk_fma_sw0(a0, bi, n1);                                    \
            n1 = pk_fma(a1, ar, n1);                                        \
            n1 = pk_fma_sw0n1(a1, ai, n1);                                  \
            v[i0] = n0; v[i1] = n1;                                         \
        );                                                                  \
    } while (0)

// gy[q] = { (c,c), (s,s) } ; n0 = c*v0 - s*v1, n1 = s*v0 + c*v1
#define RY_GATE_RB3(q) do {                                                 \
        const float2 c2 = gy[q][0];                                         \
        const float2 s2 = gy[q][1];                                         \
        FOR_PAIRS_RB3(                                                      \
            float2 n0 = pk_fma_n1(v[i1], s2, pk_mul(v[i0], c2));            \
            float2 n1 = pk_fma(v[i0], s2, pk_mul(v[i1], c2));               \
            v[i0] = n0; v[i1] = n1;                                         \
        );                                                                  \
    } while (0)

// phase: gate QB+d on reg-bit 3-d, via rb3-gate + rotation (rho^4 = id).
// `#pragma unroll 1` is the point: ONE copy of the gate body in I$.
#define M_PHASE(QB)  do {                                                   \
    _Pragma("unroll 1")                                                     \
    for (int d_ = 0; d_ < 4; ++d_) {                                        \
        M_GATE_RB3((QB) + d_);                                              \
        ROT4;                                                               \
    } } while (0)
#define RY_PHASE(QB) do {                                                   \
    _Pragma("unroll 1")                                                     \
    for (int d_ = 0; d_ < 4; ++d_) {                                        \
        RY_GATE_RB3((QB) + d_);                                             \
        ROT4;                                                               \
    } } while (0)

__global__ __launch_bounds__(TPB, 4) void vqc_kernel(
    const float* __restrict__ x,    // [B, 12]
    const float* __restrict__ th,   // [2, 12, 2]
    const float* __restrict__ lm,   // [2, 12]
    float* __restrict__ out)        // [B, 12]
{
    __shared__ float2 S[4096];
    __shared__ float2 gm[12][4];    // fused M gate, duplicated entries
    __shared__ float2 gy[12][2];    // L1 RY, duplicated (c,c),(s,s)
    __shared__ float2 coI[12];      // L0 RX half-angle (c,s)
    __shared__ float red[4 * 12];

    const int b = blockIdx.x;
    const int t = threadIdx.x;
    const int l = t & 63;
    const int w = t >> 6;

    // strength-reduced address bases
    const int kC = (t ^ (t >> 4)) & 15;
    const int VA = (t & 0xF0) | kC;
    const int VB = ((t >> 4) << 8) | kC;
    const int VC = (t << 4) | kC;
    // ring per-thread part: Ft = sg(P-image of t) (GF(2)-linear split)
    int Ft;
    {
        int yt = t ^ (t >> 1); yt ^= yt >> 2; yt ^= yt >> 4; yt ^= yt >> 8;
        int pt = (yt & 0x7FF) | ((__popc(t) & 1) << 11);
        Ft = (pt & ~15) | ((pt ^ (pt >> 4) ^ (pt >> 8)) & 15);
    }

    // ---- cooperative coefficient precompute ----
    if (t < 12) {
        float h = 0.5f * lm[t] * x[b * NQ + t];
        float c, s; __sincosf(h, &s, &c);
        coI[t] = make_float2(c, s);
    } else if (t < 24) {
        int q = t - 12;
        float h = 0.5f * th[24 + 2 * q];
        float c, s; __sincosf(h, &s, &c);
        gy[q][0] = make_float2(c, c);
        gy[q][1] = make_float2(s, s);
    } else if (t < 36) {
        int q = t - 24;
        float ha = 0.5f * lm[12 + q] * x[b * NQ + q];  // L1 RX half
        float hy = 0.5f * th[2 * q];                   // L0 RY half
        float hz = 0.5f * th[2 * q + 1];               // L0 RZ half
        float ca, sa, cy, sy, cz, sz;
        __sincosf(ha, &sa, &ca);
        __sincosf(hy, &sy, &cy);
        __sincosf(hz, &sz, &cz);
        // M = RX(a) RZ(z) RY(y) in SU(2): alpha = M00, beta = M10 (R9-verified)
        float ax = ca*cy*cz + sa*sy*sz;
        float ay = -(ca*cy*sz + sa*sy*cz);
        float bx = ca*sy*cz - sa*cy*sz;
        float by = ca*sy*sz - sa*cy*cz;
        gm[q][0] = make_float2(ax, ax);
        gm[q][1] = make_float2(-ay, ay);
        gm[q][2] = make_float2(bx, bx);
        gm[q][3] = make_float2(-by, by);
    }
    __syncthreads();                                   // B1

    float2 v[16];

    // ---- init in layout C: L0 RX product state, ring0 folded ----
    // (R10-verified) i = P^{-1}(j), j = (t<<4)|r:
    //  i0=r0^r1 (q11), i1=r1^r2 (q10), i2=r2^r3 (q9), i3=r3^t0 (q8),
    //  i4..i9 = gray(t) bits 0..5 (qubits 7..2),
    //  i10 = t6^r0^t7 (q1), i11 = r0^t7 (q0)
    {
        const int g = (t ^ (t >> 1)) & 0x3F;
        float Pt = 1.0f;
#pragma unroll
        for (int m = 0; m < 6; ++m) {
            float2 cs = coI[7 - m];
            Pt *= ((g >> m) & 1) ? cs.y : cs.x;
        }
        const int ct = __popc(g);
        const int t0 = t & 1, t7 = (t >> 7) & 1;
        const int e1 = ((t >> 6) ^ (t >> 7)) & 1;
        float2 q11 = coI[11], q10 = coI[10], q9 = coI[9],
               q8 = coI[8], q1 = coI[1], q0 = coI[0];
        const float u8  = t0 ? q8.y : q8.x;     // qubit 8, key t0^r3
        const float u8n = t0 ? q8.x : q8.y;
        const float u1  = e1 ? q1.y : q1.x;     // qubit 1, key e1^r0
        const float u1n = e1 ? q1.x : q1.y;
        const float u0  = t7 ? q0.y : q0.x;     // qubit 0, key t7^r0
        const float u0n = t7 ? q0.x : q0.y;
#pragma unroll
        for (int r = 0; r < 16; ++r) {
            const int r0 = r & 1, r1 = (r >> 1) & 1, r2 = (r >> 2) & 1,
                      r3 = (r >> 3) & 1;
            const int b11 = r0 ^ r1, b10 = r1 ^ r2, b9 = r2 ^ r3;
            float m = Pt * (b11 ? q11.y : q11.x) * (b10 ? q10.y : q10.x)
                         * (b9 ? q9.y : q9.x) * (r3 ? u8n : u8)
                         * (r0 ? u1n : u1) * (r0 ? u0n : u0);
            int k = (ct + b11 + b10 + b9 + (r3 ^ t0) + (r0 ^ e1) + (r0 ^ t7)) & 3;
            v[r].x = (k == 0) ? m : ((k == 2) ? -m : 0.0f);
            v[r].y = (k == 3) ? m : ((k == 1) ? -m : 0.0f);
        }
    }

    // ---- fused M-pass (L0 RY,RZ + L1 RX), C -> B -> A ----
    M_PHASE(8);                       // qubits 8..11 in C
    LOCAL_X(ADDR_C, ADDR_B);          // X1: wave-local
    M_PHASE(4);                       // qubits 4..7  in B
#pragma unroll
    for (int r = 0; r < 16; ++r) S[ADDR_B(r)] = v[r];
    __syncthreads();                  // B2 (cross B -> A)
#pragma unroll
    for (int r = 0; r < 16; ++r) v[r] = S[ADDR_A(r)];
    M_PHASE(0);                       // qubits 0..3  in A

    // ---- layer-1 CNOT ring: A -> A (addr = Ft ^ const-folded G(r<<8)) ----
    __syncthreads();                  // B3 (all A-reads done before scatter)
#pragma unroll
    for (int r = 0; r < 16; ++r) {
        const int jr = r << 8;
        int yr = jr ^ (jr >> 1); yr ^= yr >> 2; yr ^= yr >> 4; yr ^= yr >> 8;
        const int pr = (yr & 0x7FF) | (((__popc(jr) ^ (jr >> 11)) & 1) << 11);
        const int Gr = (pr & ~15) | ((pr ^ (pr >> 4) ^ (pr >> 8)) & 15);
        S[Ft ^ Gr] = v[r];
    }
    __syncthreads();                  // B4
#pragma unroll
    for (int r = 0; r < 16; ++r) v[r] = S[ADDR_A(r)];

    // ---- layer-1 RY (final RZ dropped), A -> B -> C ----
    RY_PHASE(0);                      // in A
    // no barrier: store hits exactly the addresses THIS thread read at the
    // B4 gather; no other thread touches these slots (R2-verified).
#pragma unroll
    for (int r = 0; r < 16; ++r) S[ADDR_A(r)] = v[r];
    __syncthreads();                  // B5 (cross A -> B)
#pragma unroll
    for (int r = 0; r < 16; ++r) v[r] = S[ADDR_B(r)];
    RY_PHASE(4);                      // in B
    LOCAL_X(ADDR_B, ADDR_C);          // X5: wave-local
    RY_PHASE(8);                      // in C

    // ---- measurement in C ----
    // qubits 8..11 <-> r bits 3..0 ; qubits 2..7 <-> lane bits 5..0
    // (lane bit k = j[4+k] = qubit 7-k) ; qubits 0,1 <-> wave bits 1,0
    float p[16];
#pragma unroll
    for (int r = 0; r < 16; ++r)
        p[r] = fmaf(v[r].x, v[r].x, v[r].y * v[r].y);
    float sA[8], dA[8];
#pragma unroll
    for (int k = 0; k < 8; ++k) {
        sA[k] = p[2 * k] + p[2 * k + 1];
        dA[k] = p[2 * k] - p[2 * k + 1];
    }
    float z11 = ((dA[0] + dA[1]) + (dA[2] + dA[3]))
              + ((dA[4] + dA[5]) + (dA[6] + dA[7]));
    float sC[4], dC[4];
#pragma unroll
    for (int k = 0; k < 4; ++k) {
        sC[k] = sA[2 * k] + sA[2 * k + 1];
        dC[k] = sA[2 * k] - sA[2 * k + 1];
    }
    float z10 = (dC[0] + dC[1]) + (dC[2] + dC[3]);
    float e0 = sC[0] + sC[1], f0 = sC[0] - sC[1];
    float e1s = sC[2] + sC[3], f1 = sC[2] - sC[3];
    float vals[5];
    vals[0] = e0 + e1s;               // ptot
    vals[1] = e0 - e1s;               // z8  (r bit3)
    vals[2] = f0 + f1;                // z9  (r bit2)
    vals[3] = z10;                    // z10 (r bit1)
    vals[4] = z11;                    // z11 (r bit0)

    // 6-stage WHT butterfly: lane L ends with sum_l (-1)^{popc(L&l)} x_l
#pragma unroll
    for (int k = 0; k < 6; ++k) {
        const float sgn = ((l >> k) & 1) ? -1.f : 1.f;
#pragma unroll
        for (int m = 0; m < 5; ++m) {
            float tmp = __shfl_xor(vals[m], 1 << k, 64);
            vals[m] = fmaf(sgn, vals[m], tmp);
        }
    }
    if (l == 0) {                     // wave totals
        red[w * 12 + 0]  = vals[0];   // ptot (for qubits 0,1)
        red[w * 12 + 8]  = vals[1];
        red[w * 12 + 9]  = vals[2];
        red[w * 12 + 10] = vals[3];
        red[w * 12 + 11] = vals[4];
    } else if (__popc(l) == 1) {      // lane-bit sums: qubits 2..7
        int q = 8 - __ffs(l);         // l=1<<k -> q = 7-k
        red[w * 12 + q] = vals[0];
    }
    __syncthreads();                  // B6
    if (t < NQ) {
        float acc = 0.f;
#pragma unroll
        for (int ww = 0; ww < 4; ++ww) {
            if (t < 2) {
                float pv = red[ww * 12 + 0];
                acc += ((ww >> (1 - t)) & 1) ? -pv : pv;
            } else {
                acc += red[ww * 12 + t];
            }
        }
        out[b * NQ + t] = acc;
    }
}

extern "C" void kernel_launch(void* const* d_in, const int* in_sizes, int n_in,
                              void* d_out, int out_size, void* d_ws, size_t ws_size,
                              hipStream_t stream) {
    const int B = in_sizes[0] / NQ;  // 1024
    vqc_kernel<<<B, TPB, 0, stream>>>((const float*)d_in[0],
                                      (const float*)d_in[1],
                                      (const float*)d_in[2],
                                      (float*)d_out);
}

// Round 9
// 72.873 us; speedup vs baseline: 1.2965x; 1.0240x over previous
//
#include <hip/hip_runtime.h>
#include <math.h>

#define NQ 12
#define TPB 256

// R19: GATE-CONSTANT HOIST. R16 counters showed VGPR_Count=64: with 32
// VGPRs of state, the compiler CANNOT keep the 36 float2 gate constants
// in registers -- it reloads them from LDS at the top of EVERY gate and
// serially waits lgkmcnt before each 64-pk burst (~60 exposed waits per
// thread ~= the unexplained 3-4x critical-path inflation; VALUBusy 20%,
// DS-pipe low, conflicts 0 -- every other theory falsified R12-R18).
// Fix: load all constants ONCE after B1 into GA/GB/GY[12] register arrays
// (72 VGPR, statically indexed); gates select the constant word via VOP3P
// op_sel/op_sel_hi on the packed-f32 source (same word-select mechanism
// R2 already uses for the src0 swap) with neg_lo/neg_hi for signs.
// __launch_bounds__(256,2) lifts the VGPR cap to 256 (est. use ~130;
// worst case 3 blocks/CU -- TLP is near-worthless per R15/R17 evidence).
// Everything else is byte-identical to R2 (fastest verified: 33.9us).
//
// Amp index j (12 bits), qubit q <-> j bit 11-q. Register layouts
// (t = thread 0..255 gives 8 bits, r = reg index 4 bits):
//   A: j = (r<<8)|t                  r = j[11:8] = qubits 0..3
//   B: j = (t[7:4]<<8)|(r<<4)|t[3:0] r = j[7:4]  = qubits 4..7
//   C: j = (t<<4)|r                  r = j[3:0]  = qubits 8..11
// B,C share wave bits j[11:10] -> B<->C roundtrips wave-local.
// Swizzle sg(j) = (j&~15)|((j^(j>>4)^(j>>8))&15); with kC=(t^(t>>4))&15:
//   sg(J_A(r)) = VA ^ 257r,  VA = (t&0xF0)|kC
//   sg(J_B(r)) = VB ^ 17r,   VB = ((t>>4)<<8)|kC
//   sg(J_C(r)) = VC ^ r,     VC = (t<<4)|kC
//   sg(P(j))   = Ft ^ G(r<<8), Ft per-thread, G const-folded
//
// Gate algebra (SU(2) [[a,-conj b],[b,conj a]], a=(ax,ay), b=(bx,by),
// A2=(ax,ay), B2=(bx,by) packed; per-term word-select, checked by hand):
//  n0 = a*v0 - conj(b)*v1:
//   t  = (ax*x0, ax*y0)                       mul  word0
//   t += (y0*(-ay), x0*(+ay))                 fma  swap0, word1, neg_lo
//   t += (x1*(-bx), y1*(-bx))                 fma  word0, neg both
//   t += (y1*(-by), x1*(+by))                 fma  swap0, word1, neg_lo
//  n1 = b*v0 + conj(a)*v1:
//   u  = (bx*x0, bx*y0)                       mul  word0
//   u += (y0*(-by), x0*(+by))                 fma  swap0, word1, neg_lo
//   u += (x1*(+ax), y1*(+ax))                 fma  word0
//   u += (y1*(+ay), x1*(-ay))                 fma  swap0, word1, neg_hi
//  RY (Y2=(c,s)): n0 = (c*x0, c*y0) + (x1*(-s), y1*(-s));
//                 n1 = (s*x0, s*y0) + (x1*(+c), y1*(+c)).
//
// Circuit (algebra verified R2-R10): init(C) = L0 RX product state with
// ring0 FOLDED via inverse perm; fused M_q = RX(L1)*RZ(L0)*RY(L0); ring1
// scatter; L1 RY (final RZ dropped); <Z_q> via partial reg-WHT + 6-stage
// lane-WHT butterfly.

#define PKMUL(d, a, b, MODS)                                          \
    asm("v_pk_mul_f32 %0, %1, %2 " MODS                               \
        : "=v"(d) : "v"(a), "v"(b))
#define PKFMA(d, a, b, c, MODS)                                       \
    asm("v_pk_fma_f32 %0, %1, %2, %3 " MODS                           \
        : "=v"(d) : "v"(a), "v"(b), "v"(c))

// variadic: commas inside the body are re-joined by __VA_ARGS__
#define FOR_PAIRS4(RB, ...) do {                                      \
    const int msk_ = 1 << (RB);                                       \
    _Pragma("unroll")                                                 \
    for (int h_ = 0; h_ < 8; ++h_) {                                  \
        const int i0 = ((h_ & ~(msk_ - 1)) << 1) | (h_ & (msk_ - 1)); \
        const int i1 = i0 | msk_;                                     \
        __VA_ARGS__;                                                  \
    } } while (0)

// strength-reduced swizzled addresses (VA/VB/VC in scope)
#define ADDR_A(r) (VA ^ (257 * (r)))
#define ADDR_B(r) (VB ^ (17 * (r)))
#define ADDR_C(r) (VC ^ (r))

// compiler-only fence for the barrier-less wave-local store->load aliasing
#define CFENCE asm volatile("" ::: "memory")

// wave-local roundtrip (same-wave LDS ordering, no barrier)
#define LOCAL_X(AS, AD) do {                                          \
    _Pragma("unroll")                                                 \
    for (int r_ = 0; r_ < 16; ++r_) S[AS(r_)] = v[r_];                \
    CFENCE;                                                           \
    _Pragma("unroll")                                                 \
    for (int r_ = 0; r_ < 16; ++r_) v[r_] = S[AD(r_)];                \
  } while (0)

// SU(2) gate from register-resident packed constants (see header algebra)
#define M_GATE(q, RB) do {                                                  \
        const float2 A2 = GA[q];                                            \
        const float2 B2 = GB[q];                                            \
        FOR_PAIRS4(RB,                                                      \
            const float2 a0 = v[i0];                                        \
            const float2 a1 = v[i1];                                        \
            float2 t, u;                                                    \
            PKMUL(t, a0, A2, "op_sel_hi:[1,0]");                            \
            PKFMA(t, a0, A2, t,                                             \
                  "op_sel:[1,1,0] op_sel_hi:[0,1,1] neg_lo:[0,1,0]");       \
            PKFMA(t, a1, B2, t,                                             \
                  "op_sel_hi:[1,0,1] neg_lo:[0,1,0] neg_hi:[0,1,0]");       \
            PKFMA(t, a1, B2, t,                                             \
                  "op_sel:[1,1,0] op_sel_hi:[0,1,1] neg_lo:[0,1,0]");       \
            PKMUL(u, a0, B2, "op_sel_hi:[1,0]");                            \
            PKFMA(u, a0, B2, u,                                             \
                  "op_sel:[1,1,0] op_sel_hi:[0,1,1] neg_lo:[0,1,0]");       \
            PKFMA(u, a1, A2, u, "op_sel_hi:[1,0,1]");                       \
            PKFMA(u, a1, A2, u,                                             \
                  "op_sel:[1,1,0] op_sel_hi:[0,1,1] neg_hi:[0,1,0]");       \
            v[i0] = t; v[i1] = u;                                           \
        );                                                                  \
    } while (0)

#define RY_GATE(q, RB) do {                                                 \
        const float2 Y2 = GY[q];                                            \
        FOR_PAIRS4(RB,                                                      \
            float2 t, u;                                                    \
            PKMUL(t, v[i0], Y2, "op_sel_hi:[1,0]");                         \
            PKFMA(t, v[i1], Y2, t,                                          \
                  "op_sel:[0,1,0] op_sel_hi:[1,1,1] "                       \
                  "neg_lo:[0,1,0] neg_hi:[0,1,0]");                         \
            PKMUL(u, v[i0], Y2, "op_sel:[0,1] op_sel_hi:[1,1]");            \
            PKFMA(u, v[i1], Y2, u, "op_sel_hi:[1,0,1]");                    \
            v[i0] = t; v[i1] = u;                                           \
        );                                                                  \
    } while (0)

// phase: gate qubit QB+d on r-bit 3-d (holds for A, B, C alike)
#define M_PHASE(QB)  do { _Pragma("unroll")                                 \
    for (int d_ = 0; d_ < 4; ++d_) M_GATE((QB) + d_, 3 - d_); } while (0)
#define RY_PHASE(QB) do { _Pragma("unroll")                                 \
    for (int d_ = 0; d_ < 4; ++d_) RY_GATE((QB) + d_, 3 - d_); } while (0)

__global__ __launch_bounds__(TPB, 2) void vqc_kernel(
    const float* __restrict__ x,    // [B, 12]
    const float* __restrict__ th,   // [2, 12, 2]
    const float* __restrict__ lm,   // [2, 12]
    float* __restrict__ out)        // [B, 12]
{
    __shared__ float2 S[4096];
    __shared__ float2 gmA[12];      // fused M gate: (ax, ay)
    __shared__ float2 gmB[12];      // fused M gate: (bx, by)
    __shared__ float2 gyS[12];      // L1 RY: (c, s)
    __shared__ float2 coI[12];      // L0 RX half-angle (c,s)
    __shared__ float red[4 * 12];

    const int b = blockIdx.x;
    const int t = threadIdx.x;
    const int l = t & 63;
    const int w = t >> 6;

    // strength-reduced address bases
    const int kC = (t ^ (t >> 4)) & 15;
    const int VA = (t & 0xF0) | kC;
    const int VB = ((t >> 4) << 8) | kC;
    const int VC = (t << 4) | kC;
    // ring per-thread part: Ft = sg(P-image of t) (GF(2)-linear split)
    int Ft;
    {
        int yt = t ^ (t >> 1); yt ^= yt >> 2; yt ^= yt >> 4; yt ^= yt >> 8;
        int pt = (yt & 0x7FF) | ((__popc(t) & 1) << 11);
        Ft = (pt & ~15) | ((pt ^ (pt >> 4) ^ (pt >> 8)) & 15);
    }

    // ---- cooperative coefficient precompute ----
    if (t < 12) {
        float h = 0.5f * lm[t] * x[b * NQ + t];
        float c, s; __sincosf(h, &s, &c);
        coI[t] = make_float2(c, s);
    } else if (t < 24) {
        int q = t - 12;
        float h = 0.5f * th[24 + 2 * q];
        float c, s; __sincosf(h, &s, &c);
        gyS[q] = make_float2(c, s);
    } else if (t < 36) {
        int q = t - 24;
        float ha = 0.5f * lm[12 + q] * x[b * NQ + q];  // L1 RX half
        float hy = 0.5f * th[2 * q];                   // L0 RY half
        float hz = 0.5f * th[2 * q + 1];               // L0 RZ half
        float ca, sa, cy, sy, cz, sz;
        __sincosf(ha, &sa, &ca);
        __sincosf(hy, &sy, &cy);
        __sincosf(hz, &sz, &cz);
        // M = RX(a) RZ(z) RY(y) in SU(2): alpha = M00, beta = M10 (R9-verified)
        float ax = ca*cy*cz + sa*sy*sz;
        float ay = -(ca*cy*sz + sa*sy*cz);
        float bx = ca*sy*cz - sa*cy*sz;
        float by = ca*sy*sz - sa*cy*cz;
        gmA[q] = make_float2(ax, ay);
        gmB[q] = make_float2(bx, by);
    }
    __syncthreads();                                   // B1

    // ---- hoist ALL gate constants into registers (once) ----
    float2 GA[12], GB[12], GY[12];
#pragma unroll
    for (int q = 0; q < 12; ++q) {
        GA[q] = gmA[q];
        GB[q] = gmB[q];
        GY[q] = gyS[q];
    }

    float2 v[16];

    // ---- init in layout C: L0 RX product state, ring0 folded ----
    // (R10-verified) i = P^{-1}(j), j = (t<<4)|r:
    //  i0=r0^r1 (q11), i1=r1^r2 (q10), i2=r2^r3 (q9), i3=r3^t0 (q8),
    //  i4..i9 = gray(t) bits 0..5 (qubits 7..2),
    //  i10 = t6^r0^t7 (q1), i11 = r0^t7 (q0)
    {
        const int g = (t ^ (t >> 1)) & 0x3F;
        float Pt = 1.0f;
#pragma unroll
        for (int m = 0; m < 6; ++m) {
            float2 cs = coI[7 - m];
            Pt *= ((g >> m) & 1) ? cs.y : cs.x;
        }
        const int ct = __popc(g);
        const int t0 = t & 1, t7 = (t >> 7) & 1;
        const int e1 = ((t >> 6) ^ (t >> 7)) & 1;
        float2 q11 = coI[11], q10 = coI[10], q9 = coI[9],
               q8 = coI[8], q1 = coI[1], q0 = coI[0];
        const float u8  = t0 ? q8.y : q8.x;     // qubit 8, key t0^r3
        const float u8n = t0 ? q8.x : q8.y;
        const float u1  = e1 ? q1.y : q1.x;     // qubit 1, key e1^r0
        const float u1n = e1 ? q1.x : q1.y;
        const float u0  = t7 ? q0.y : q0.x;     // qubit 0, key t7^r0
        const float u0n = t7 ? q0.x : q0.y;
#pragma unroll
        for (int r = 0; r < 16; ++r) {
            const int r0 = r & 1, r1 = (r >> 1) & 1, r2 = (r >> 2) & 1,
                      r3 = (r >> 3) & 1;
            const int b11 = r0 ^ r1, b10 = r1 ^ r2, b9 = r2 ^ r3;
            float m = Pt * (b11 ? q11.y : q11.x) * (b10 ? q10.y : q10.x)
                         * (b9 ? q9.y : q9.x) * (r3 ? u8n : u8)
                         * (r0 ? u1n : u1) * (r0 ? u0n : u0);
            int k = (ct + b11 + b10 + b9 + (r3 ^ t0) + (r0 ^ e1) + (r0 ^ t7)) & 3;
            v[r].x = (k == 0) ? m : ((k == 2) ? -m : 0.0f);
            v[r].y = (k == 3) ? m : ((k == 1) ? -m : 0.0f);
        }
    }

    // ---- fused M-pass (L0 RY,RZ + L1 RX), C -> B -> A ----
    M_PHASE(8);                       // qubits 8..11 in C
    LOCAL_X(ADDR_C, ADDR_B);          // X1: wave-local
    M_PHASE(4);                       // qubits 4..7  in B
#pragma unroll
    for (int r = 0; r < 16; ++r) S[ADDR_B(r)] = v[r];
    __syncthreads();                  // B2 (cross B -> A)
#pragma unroll
    for (int r = 0; r < 16; ++r) v[r] = S[ADDR_A(r)];
    M_PHASE(0);                       // qubits 0..3  in A

    // ---- layer-1 CNOT ring: A -> A (addr = Ft ^ const-folded G(r<<8)) ----
    __syncthreads();                  // B3 (all A-reads done before scatter)
#pragma unroll
    for (int r = 0; r < 16; ++r) {
        const int jr = r << 8;
        int yr = jr ^ (jr >> 1); yr ^= yr >> 2; yr ^= yr >> 4; yr ^= yr >> 8;
        const int pr = (yr & 0x7FF) | (((__popc(jr) ^ (jr >> 11)) & 1) << 11);
        const int Gr = (pr & ~15) | ((pr ^ (pr >> 4) ^ (pr >> 8)) & 15);
        S[Ft ^ Gr] = v[r];
    }
    __syncthreads();                  // B4
#pragma unroll
    for (int r = 0; r < 16; ++r) v[r] = S[ADDR_A(r)];

    // ---- layer-1 RY (final RZ dropped), A -> B -> C ----
    RY_PHASE(0);                      // in A
    // no barrier: store hits exactly the addresses THIS thread read at the
    // B4 gather; no other thread touches these slots (R2-verified).
#pragma unroll
    for (int r = 0; r < 16; ++r) S[ADDR_A(r)] = v[r];
    __syncthreads();                  // B5 (cross A -> B)
#pragma unroll
    for (int r = 0; r < 16; ++r) v[r] = S[ADDR_B(r)];
    RY_PHASE(4);                      // in B
    LOCAL_X(ADDR_B, ADDR_C);          // X5: wave-local
    RY_PHASE(8);                      // in C

    // ---- measurement in C ----
    // qubits 8..11 <-> r bits 3..0 ; qubits 2..7 <-> lane bits 5..0
    // (lane bit k = j[4+k] = qubit 7-k) ; qubits 0,1 <-> wave bits 1,0
    float p[16];
#pragma unroll
    for (int r = 0; r < 16; ++r)
        p[r] = fmaf(v[r].x, v[r].x, v[r].y * v[r].y);
    float sA[8], dA[8];
#pragma unroll
    for (int k = 0; k < 8; ++k) {
        sA[k] = p[2 * k] + p[2 * k + 1];
        dA[k] = p[2 * k] - p[2 * k + 1];
    }
    float z11 = ((dA[0] + dA[1]) + (dA[2] + dA[3]))
              + ((dA[4] + dA[5]) + (dA[6] + dA[7]));
    float sC[4], dC[4];
#pragma unroll
    for (int k = 0; k < 4; ++k) {
        sC[k] = sA[2 * k] + sA[2 * k + 1];
        dC[k] = sA[2 * k] - sA[2 * k + 1];
    }
    float z10 = (dC[0] + dC[1]) + (dC[2] + dC[3]);
    float e0 = sC[0] + sC[1], f0 = sC[0] - sC[1];
    float e1s = sC[2] + sC[3], f1 = sC[2] - sC[3];
    float vals[5];
    vals[0] = e0 + e1s;               // ptot
    vals[1] = e0 - e1s;               // z8  (r bit3)
    vals[2] = f0 + f1;                // z9  (r bit2)
    vals[3] = z10;                    // z10 (r bit1)
    vals[4] = z11;                    // z11 (r bit0)

    // 6-stage WHT butterfly: lane L ends with sum_l (-1)^{popc(L&l)} x_l
#pragma unroll
    for (int k = 0; k < 6; ++k) {
        const float sgn = ((l >> k) & 1) ? -1.f : 1.f;
#pragma unroll
        for (int m = 0; m < 5; ++m) {
            float tmp = __shfl_xor(vals[m], 1 << k, 64);
            vals[m] = fmaf(sgn, vals[m], tmp);
        }
    }
    if (l == 0) {                     // wave totals
        red[w * 12 + 0]  = vals[0];   // ptot (for qubits 0,1)
        red[w * 12 + 8]  = vals[1];
        red[w * 12 + 9]  = vals[2];
        red[w * 12 + 10] = vals[3];
        red[w * 12 + 11] = vals[4];
    } else if (__popc(l) == 1) {      // lane-bit sums: qubits 2..7
        int q = 8 - __ffs(l);         // l=1<<k -> q = 7-k
        red[w * 12 + q] = vals[0];
    }
    __syncthreads();                  // B6
    if (t < NQ) {
        float acc = 0.f;
#pragma unroll
        for (int ww = 0; ww < 4; ++ww) {
            if (t < 2) {
                float pv = red[ww * 12 + 0];
                acc += ((ww >> (1 - t)) & 1) ? -pv : pv;
            } else {
                acc += red[ww * 12 + t];
            }
        }
        out[b * NQ + t] = acc;
    }
}

extern "C" void kernel_launch(void* const* d_in, const int* in_sizes, int n_in,
                              void* d_out, int out_size, void* d_ws, size_t ws_size,
                              hipStream_t stream) {
    const int B = in_sizes[0] / NQ;  // 1024
    vqc_kernel<<<B, TPB, 0, stream>>>((const float*)d_in[0],
                                      (const float*)d_in[1],
                                      (const float*)d_in[2],
                                      (float*)d_out);
}

// Round 10
// 72.397 us; speedup vs baseline: 1.3050x; 1.0066x over previous
//
#include <hip/hip_runtime.h>
#include <math.h>

#define NQ 12
#define TPB 256

// R20: SOFTWARE-PIPELINED GATE MATH. The surviving theory after R12-R19:
// all FLOPs are inline-asm statements; LLVM preserves asm order and never
// interleaves them, so each pair's 4-deep dependent pk chain stalls the
// in-order wave ~4-8 cyc per op. Evidence: R17 = 12 cyc/inst at 1
// wave/SIMD; R16 VALUBusy 20% solo; every structural rewrite null (they
// all kept the same serial chains); R12 helped proportionally to ops cut.
// Fix: capture olds (o0/o1[8]), then emit the gate as 8 sweeps of 8
// INDEPENDENT ops (all pairs' step k together, t/u sweeps alternating):
// dependent ops on one accumulator are 16 instrs (~32 cyc) apart ->
// latency hidden even at 1 wave/SIMD. In-place accumulate via "+v" PKACC
// with R19's exact harness-verified op_sel/neg strings. +32 VGPR.
// Everything else byte-identical to R19 (best: 72.87 total).
//
// Amp index j (12 bits), qubit q <-> j bit 11-q. Register layouts
// (t = thread 0..255 gives 8 bits, r = reg index 4 bits):
//   A: j = (r<<8)|t                  r = j[11:8] = qubits 0..3
//   B: j = (t[7:4]<<8)|(r<<4)|t[3:0] r = j[7:4]  = qubits 4..7
//   C: j = (t<<4)|r                  r = j[3:0]  = qubits 8..11
// B,C share wave bits j[11:10] -> B<->C roundtrips wave-local.
// Swizzle sg(j) = (j&~15)|((j^(j>>4)^(j>>8))&15); with kC=(t^(t>>4))&15:
//   sg(J_A(r)) = VA ^ 257r,  VA = (t&0xF0)|kC
//   sg(J_B(r)) = VB ^ 17r,   VB = ((t>>4)<<8)|kC
//   sg(J_C(r)) = VC ^ r,     VC = (t<<4)|kC
//   sg(P(j))   = Ft ^ G(r<<8), Ft per-thread, G const-folded
//
// Gate algebra (SU(2) [[a,-conj b],[b,conj a]], a=(ax,ay), b=(bx,by),
// A2=(ax,ay), B2=(bx,by) packed; per-term word-select, R19-verified):
//  n0 = a*v0 - conj(b)*v1 ; n1 = b*v0 + conj(a)*v1
//  RY (Y2=(c,s)): n0 = c*v0 - s*v1 ; n1 = s*v0 + c*v1
//
// Circuit (algebra verified R2-R10): init(C) = L0 RX product state with
// ring0 FOLDED via inverse perm; fused M_q = RX(L1)*RZ(L0)*RY(L0); ring1
// scatter; L1 RY (final RZ dropped); <Z_q> via partial reg-WHT + 6-stage
// lane-WHT butterfly.

#define PKMUL(d, a, b, MODS)                                          \
    asm("v_pk_mul_f32 %0, %1, %2 " MODS                               \
        : "=v"(d) : "v"(a), "v"(b))
// in-place accumulate: d = a*b + d (src2 tied to dest)
#define PKACC(d, a, b, MODS)                                          \
    asm("v_pk_fma_f32 %0, %1, %2, %0 " MODS                           \
        : "+v"(d) : "v"(a), "v"(b))

// 8 independent pair-slots of reg-bit RB (msk_ in scope)
#define FOR8(...) do {                                                \
    _Pragma("unroll")                                                 \
    for (int h_ = 0; h_ < 8; ++h_) {                                  \
        const int i0 = ((h_ & ~(msk_ - 1)) << 1) | (h_ & (msk_ - 1)); \
        const int i1 = i0 | msk_;                                     \
        __VA_ARGS__;                                                  \
    } } while (0)

// strength-reduced swizzled addresses (VA/VB/VC in scope)
#define ADDR_A(r) (VA ^ (257 * (r)))
#define ADDR_B(r) (VB ^ (17 * (r)))
#define ADDR_C(r) (VC ^ (r))

// compiler-only fence for the barrier-less wave-local store->load aliasing
#define CFENCE asm volatile("" ::: "memory")

// wave-local roundtrip (same-wave LDS ordering, no barrier)
#define LOCAL_X(AS, AD) do {                                          \
    _Pragma("unroll")                                                 \
    for (int r_ = 0; r_ < 16; ++r_) S[AS(r_)] = v[r_];                \
    CFENCE;                                                           \
    _Pragma("unroll")                                                 \
    for (int r_ = 0; r_ < 16; ++r_) v[r_] = S[AD(r_)];                \
  } while (0)

// SU(2) gate, software-pipelined: 8 sweeps of 8 independent ops.
// Dependent ops on one accumulator are 16 instrs apart.
#define M_GATE(q, RB) do {                                                  \
        const float2 A2 = GA[q];                                            \
        const float2 B2 = GB[q];                                            \
        const int msk_ = 1 << (RB);                                         \
        float2 o0[8], o1[8];                                                \
        FOR8( o0[h_] = v[i0]; o1[h_] = v[i1]; );                            \
        FOR8( PKMUL(v[i0], o0[h_], A2, "op_sel_hi:[1,0]"); );               \
        FOR8( PKMUL(v[i1], o0[h_], B2, "op_sel_hi:[1,0]"); );               \
        FOR8( PKACC(v[i0], o0[h_], A2,                                      \
                    "op_sel:[1,1,0] op_sel_hi:[0,1,1] neg_lo:[0,1,0]"); );  \
        FOR8( PKACC(v[i1], o0[h_], B2,                                      \
                    "op_sel:[1,1,0] op_sel_hi:[0,1,1] neg_lo:[0,1,0]"); );  \
        FOR8( PKACC(v[i0], o1[h_], B2,                                      \
                    "op_sel_hi:[1,0,1] neg_lo:[0,1,0] neg_hi:[0,1,0]"); );  \
        FOR8( PKACC(v[i1], o1[h_], A2, "op_sel_hi:[1,0,1]"); );             \
        FOR8( PKACC(v[i0], o1[h_], B2,                                      \
                    "op_sel:[1,1,0] op_sel_hi:[0,1,1] neg_lo:[0,1,0]"); );  \
        FOR8( PKACC(v[i1], o1[h_], A2,                                      \
                    "op_sel:[1,1,0] op_sel_hi:[0,1,1] neg_hi:[0,1,0]"); );  \
    } while (0)

#define RY_GATE(q, RB) do {                                                 \
        const float2 Y2 = GY[q];                                            \
        const int msk_ = 1 << (RB);                                         \
        float2 o0[8], o1[8];                                                \
        FOR8( o0[h_] = v[i0]; o1[h_] = v[i1]; );                            \
        FOR8( PKMUL(v[i0], o0[h_], Y2, "op_sel_hi:[1,0]"); );               \
        FOR8( PKMUL(v[i1], o0[h_], Y2, "op_sel:[0,1] op_sel_hi:[1,1]"); );  \
        FOR8( PKACC(v[i0], o1[h_], Y2,                                      \
                    "op_sel:[0,1,0] op_sel_hi:[1,1,1] "                     \
                    "neg_lo:[0,1,0] neg_hi:[0,1,0]"); );                    \
        FOR8( PKACC(v[i1], o1[h_], Y2, "op_sel_hi:[1,0,1]"); );             \
    } while (0)

// phase: gate qubit QB+d on r-bit 3-d (holds for A, B, C alike)
#define M_PHASE(QB)  do { _Pragma("unroll")                                 \
    for (int d_ = 0; d_ < 4; ++d_) M_GATE((QB) + d_, 3 - d_); } while (0)
#define RY_PHASE(QB) do { _Pragma("unroll")                                 \
    for (int d_ = 0; d_ < 4; ++d_) RY_GATE((QB) + d_, 3 - d_); } while (0)

__global__ __launch_bounds__(TPB, 2) void vqc_kernel(
    const float* __restrict__ x,    // [B, 12]
    const float* __restrict__ th,   // [2, 12, 2]
    const float* __restrict__ lm,   // [2, 12]
    float* __restrict__ out)        // [B, 12]
{
    __shared__ float2 S[4096];
    __shared__ float2 gmA[12];      // fused M gate: (ax, ay)
    __shared__ float2 gmB[12];      // fused M gate: (bx, by)
    __shared__ float2 gyS[12];      // L1 RY: (c, s)
    __shared__ float2 coI[12];      // L0 RX half-angle (c,s)
    __shared__ float red[4 * 12];

    const int b = blockIdx.x;
    const int t = threadIdx.x;
    const int l = t & 63;
    const int w = t >> 6;

    // strength-reduced address bases
    const int kC = (t ^ (t >> 4)) & 15;
    const int VA = (t & 0xF0) | kC;
    const int VB = ((t >> 4) << 8) | kC;
    const int VC = (t << 4) | kC;
    // ring per-thread part: Ft = sg(P-image of t) (GF(2)-linear split)
    int Ft;
    {
        int yt = t ^ (t >> 1); yt ^= yt >> 2; yt ^= yt >> 4; yt ^= yt >> 8;
        int pt = (yt & 0x7FF) | ((__popc(t) & 1) << 11);
        Ft = (pt & ~15) | ((pt ^ (pt >> 4) ^ (pt >> 8)) & 15);
    }

    // ---- cooperative coefficient precompute ----
    if (t < 12) {
        float h = 0.5f * lm[t] * x[b * NQ + t];
        float c, s; __sincosf(h, &s, &c);
        coI[t] = make_float2(c, s);
    } else if (t < 24) {
        int q = t - 12;
        float h = 0.5f * th[24 + 2 * q];
        float c, s; __sincosf(h, &s, &c);
        gyS[q] = make_float2(c, s);
    } else if (t < 36) {
        int q = t - 24;
        float ha = 0.5f * lm[12 + q] * x[b * NQ + q];  // L1 RX half
        float hy = 0.5f * th[2 * q];                   // L0 RY half
        float hz = 0.5f * th[2 * q + 1];               // L0 RZ half
        float ca, sa, cy, sy, cz, sz;
        __sincosf(ha, &sa, &ca);
        __sincosf(hy, &sy, &cy);
        __sincosf(hz, &sz, &cz);
        // M = RX(a) RZ(z) RY(y) in SU(2): alpha = M00, beta = M10 (R9-verified)
        float ax = ca*cy*cz + sa*sy*sz;
        float ay = -(ca*cy*sz + sa*sy*cz);
        float bx = ca*sy*cz - sa*cy*sz;
        float by = ca*sy*sz - sa*cy*cz;
        gmA[q] = make_float2(ax, ay);
        gmB[q] = make_float2(bx, by);
    }
    __syncthreads();                                   // B1

    // ---- hoist ALL gate constants into registers (once, R19) ----
    float2 GA[12], GB[12], GY[12];
#pragma unroll
    for (int q = 0; q < 12; ++q) {
        GA[q] = gmA[q];
        GB[q] = gmB[q];
        GY[q] = gyS[q];
    }

    float2 v[16];

    // ---- init in layout C: L0 RX product state, ring0 folded ----
    // (R10-verified) i = P^{-1}(j), j = (t<<4)|r:
    //  i0=r0^r1 (q11), i1=r1^r2 (q10), i2=r2^r3 (q9), i3=r3^t0 (q8),
    //  i4..i9 = gray(t) bits 0..5 (qubits 7..2),
    //  i10 = t6^r0^t7 (q1), i11 = r0^t7 (q0)
    {
        const int g = (t ^ (t >> 1)) & 0x3F;
        float Pt = 1.0f;
#pragma unroll
        for (int m = 0; m < 6; ++m) {
            float2 cs = coI[7 - m];
            Pt *= ((g >> m) & 1) ? cs.y : cs.x;
        }
        const int ct = __popc(g);
        const int t0 = t & 1, t7 = (t >> 7) & 1;
        const int e1 = ((t >> 6) ^ (t >> 7)) & 1;
        float2 q11 = coI[11], q10 = coI[10], q9 = coI[9],
               q8 = coI[8], q1 = coI[1], q0 = coI[0];
        const float u8  = t0 ? q8.y : q8.x;     // qubit 8, key t0^r3
        const float u8n = t0 ? q8.x : q8.y;
        const float u1  = e1 ? q1.y : q1.x;     // qubit 1, key e1^r0
        const float u1n = e1 ? q1.x : q1.y;
        const float u0  = t7 ? q0.y : q0.x;     // qubit 0, key t7^r0
        const float u0n = t7 ? q0.x : q0.y;
#pragma unroll
        for (int r = 0; r < 16; ++r) {
            const int r0 = r & 1, r1 = (r >> 1) & 1, r2 = (r >> 2) & 1,
                      r3 = (r >> 3) & 1;
            const int b11 = r0 ^ r1, b10 = r1 ^ r2, b9 = r2 ^ r3;
            float m = Pt * (b11 ? q11.y : q11.x) * (b10 ? q10.y : q10.x)
                         * (b9 ? q9.y : q9.x) * (r3 ? u8n : u8)
                         * (r0 ? u1n : u1) * (r0 ? u0n : u0);
            int k = (ct + b11 + b10 + b9 + (r3 ^ t0) + (r0 ^ e1) + (r0 ^ t7)) & 3;
            v[r].x = (k == 0) ? m : ((k == 2) ? -m : 0.0f);
            v[r].y = (k == 3) ? m : ((k == 1) ? -m : 0.0f);
        }
    }

    // ---- fused M-pass (L0 RY,RZ + L1 RX), C -> B -> A ----
    M_PHASE(8);                       // qubits 8..11 in C
    LOCAL_X(ADDR_C, ADDR_B);          // X1: wave-local
    M_PHASE(4);                       // qubits 4..7  in B
#pragma unroll
    for (int r = 0; r < 16; ++r) S[ADDR_B(r)] = v[r];
    __syncthreads();                  // B2 (cross B -> A)
#pragma unroll
    for (int r = 0; r < 16; ++r) v[r] = S[ADDR_A(r)];
    M_PHASE(0);                       // qubits 0..3  in A

    // ---- layer-1 CNOT ring: A -> A (addr = Ft ^ const-folded G(r<<8)) ----
    __syncthreads();                  // B3 (all A-reads done before scatter)
#pragma unroll
    for (int r = 0; r < 16; ++r) {
        const int jr = r << 8;
        int yr = jr ^ (jr >> 1); yr ^= yr >> 2; yr ^= yr >> 4; yr ^= yr >> 8;
        const int pr = (yr & 0x7FF) | (((__popc(jr) ^ (jr >> 11)) & 1) << 11);
        const int Gr = (pr & ~15) | ((pr ^ (pr >> 4) ^ (pr >> 8)) & 15);
        S[Ft ^ Gr] = v[r];
    }
    __syncthreads();                  // B4
#pragma unroll
    for (int r = 0; r < 16; ++r) v[r] = S[ADDR_A(r)];

    // ---- layer-1 RY (final RZ dropped), A -> B -> C ----
    RY_PHASE(0);                      // in A
    // no barrier: store hits exactly the addresses THIS thread read at the
    // B4 gather; no other thread touches these slots (R2-verified).
#pragma unroll
    for (int r = 0; r < 16; ++r) S[ADDR_A(r)] = v[r];
    __syncthreads();                  // B5 (cross A -> B)
#pragma unroll
    for (int r = 0; r < 16; ++r) v[r] = S[ADDR_B(r)];
    RY_PHASE(4);                      // in B
    LOCAL_X(ADDR_B, ADDR_C);          // X5: wave-local
    RY_PHASE(8);                      // in C

    // ---- measurement in C ----
    // qubits 8..11 <-> r bits 3..0 ; qubits 2..7 <-> lane bits 5..0
    // (lane bit k = j[4+k] = qubit 7-k) ; qubits 0,1 <-> wave bits 1,0
    float p[16];
#pragma unroll
    for (int r = 0; r < 16; ++r)
        p[r] = fmaf(v[r].x, v[r].x, v[r].y * v[r].y);
    float sA[8], dA[8];
#pragma unroll
    for (int k = 0; k < 8; ++k) {
        sA[k] = p[2 * k] + p[2 * k + 1];
        dA[k] = p[2 * k] - p[2 * k + 1];
    }
    float z11 = ((dA[0] + dA[1]) + (dA[2] + dA[3]))
              + ((dA[4] + dA[5]) + (dA[6] + dA[7]));
    float sC[4], dC[4];
#pragma unroll
    for (int k = 0; k < 4; ++k) {
        sC[k] = sA[2 * k] + sA[2 * k + 1];
        dC[k] = sA[2 * k] - sA[2 * k + 1];
    }
    float z10 = (dC[0] + dC[1]) + (dC[2] + dC[3]);
    float e0 = sC[0] + sC[1], f0 = sC[0] - sC[1];
    float e1s = sC[2] + sC[3], f1 = sC[2] - sC[3];
    float vals[5];
    vals[0] = e0 + e1s;               // ptot
    vals[1] = e0 - e1s;               // z8  (r bit3)
    vals[2] = f0 + f1;                // z9  (r bit2)
    vals[3] = z10;                    // z10 (r bit1)
    vals[4] = z11;                    // z11 (r bit0)

    // 6-stage WHT butterfly: lane L ends with sum_l (-1)^{popc(L&l)} x_l
#pragma unroll
    for (int k = 0; k < 6; ++k) {
        const float sgn = ((l >> k) & 1) ? -1.f : 1.f;
#pragma unroll
        for (int m = 0; m < 5; ++m) {
            float tmp = __shfl_xor(vals[m], 1 << k, 64);
            vals[m] = fmaf(sgn, vals[m], tmp);
        }
    }
    if (l == 0) {                     // wave totals
        red[w * 12 + 0]  = vals[0];   // ptot (for qubits 0,1)
        red[w * 12 + 8]  = vals[1];
        red[w * 12 + 9]  = vals[2];
        red[w * 12 + 10] = vals[3];
        red[w * 12 + 11] = vals[4];
    } else if (__popc(l) == 1) {      // lane-bit sums: qubits 2..7
        int q = 8 - __ffs(l);         // l=1<<k -> q = 7-k
        red[w * 12 + q] = vals[0];
    }
    __syncthreads();                  // B6
    if (t < NQ) {
        float acc = 0.f;
#pragma unroll
        for (int ww = 0; ww < 4; ++ww) {
            if (t < 2) {
                float pv = red[ww * 12 + 0];
                acc += ((ww >> (1 - t)) & 1) ? -pv : pv;
            } else {
                acc += red[ww * 12 + t];
            }
        }
        out[b * NQ + t] = acc;
    }
}

extern "C" void kernel_launch(void* const* d_in, const int* in_sizes, int n_in,
                              void* d_out, int out_size, void* d_ws, size_t ws_size,
                              hipStream_t stream) {
    const int B = in_sizes[0] / NQ;  // 1024
    vqc_kernel<<<B, TPB, 0, stream>>>((const float*)d_in[0],
                                      (const float*)d_in[1],
                                      (const float*)d_in[2],
                                      (float*)d_out);
}